// Round 12
// baseline (159.230 us; speedup 1.0000x reference)
//
#include <hip/hip_runtime.h>

#define TT 1024
#define LL 64
#define BB 256             // batch
#define SEG 32             // time-steps per segment
#define NSEG 32            // segments per sequence
#define NITEM (BB * NSEG)  // 8192 work items
#define WARM 8             // warm-up: contraction <= 0.462/step
#define LOG2E 1.44269504088896340736f
#define LN2   0.69314718055994530942f

typedef __fp16 half2v __attribute__((ext_vector_type(2)));
__device__ __forceinline__ half2v int_as_h2(int x) { union { int i; half2v h; } u; u.i = x; return u.h; }
__device__ __forceinline__ int h2_as_int(half2v x) { union { int i; half2v h; } u; u.h = x; return u.i; }

// PERSISTENT WAVES + WORK-STEALING QUEUE. 1024 blocks x 4 waves = 4096
// persistent waves, ~4/SIMD co-resident. Each wave computes E = exp(trans)
// ONCE (amortized over all items it grabs), then pulls tickets from a global
// atomic counter. Ticket -> (b, s): b = ticket&255, s = 31 - (ticket>>8)
// (s DESCENDING so the mostly-inactive high-s items drain first and the
// queue tail is uniform always-active low-s items). Dynamic stealing makes
// per-CU load self-balancing -- fixes the static-map imbalance that capped
// rounds 8-11 (each CU was welded to 4 sequences; wall = worst CU ~ 2x mean).
// Deterministic: every ticket is processed exactly once and part[ticket]
// depends only on the ticket, not on which wave runs it.
//
// Segment math (identical to rounds 7-11, absmax 0.0): wave processes
// t in [1+32s, min(+32, slen)), warm-started WARM steps earlier (positive
// transfer operator: Hilbert diameter of E <= 2 -> contraction 0.462/step).
// delta = A(u@hi)-A(u@lo) telescopes to log_norm; segment 0 exact from t=0.
// Per step, one state column per lane:
//   v_j = (sum_m pair_m(u) . ej[m]) * exp(logit[t][j])   32 readlane + 32 fdot2
//   renorm by exact pow-2 of v_0 (readfirstlane exponent), C += e
//   repack pairs via 2 ds_bpermute + cvt_pkrtz
// Logit rows in an 8-slot named register ring (true distance-8 prefetch).

__global__ __launch_bounds__(256) void crf_seg_kernel(
    const float* __restrict__ logits,    // [B][T][L]
    const int*   __restrict__ labels,    // [B][T]
    const int*   __restrict__ seq_lens,  // [B]
    const float* __restrict__ trans,     // [L][L]
    unsigned int* __restrict__ counter,  // [1] ticket counter (zeroed per launch)
    float*       __restrict__ part)      // [NITEM]
{
    const int lane = threadIdx.x & 63;

    // ---- one-time per wave: E-column pairs for this lane's column j = lane ----
    int ej[32];
    #pragma unroll
    for (int m = 0; m < 32; ++m) {
        half2v pp;
        pp[0] = (__fp16)__builtin_amdgcn_exp2f(trans[(2 * m)     * LL + lane] * LOG2E);
        pp[1] = (__fp16)__builtin_amdgcn_exp2f(trans[(2 * m + 1) * LL + lane] * LOG2E);
        ej[m] = h2_as_int(pp);
    }
    const int pad0 = (lane & 31) << 3;     // bpermute byte addr of lane 2k
    const int pad1 = pad0 + 4;             // lane 2k+1

#define RENORM(V) { \
    int ebits = (__builtin_amdgcn_readfirstlane(__float_as_int(V)) >> 23) & 0xFF; \
    C += ebits - 127; \
    float scl = __int_as_float((254 - ebits) << 23); \
    u = (V) * scl; \
}
#define PACK() { \
    int pa_ = __builtin_amdgcn_ds_bpermute(pad0, __float_as_int(u)); \
    int pb_ = __builtin_amdgcn_ds_bpermute(pad1, __float_as_int(u)); \
    upk = h2_as_int(__builtin_amdgcn_cvt_pkrtz(__int_as_float(pa_), __int_as_float(pb_))); \
}
#define MEASURE(OUT) { \
    float us_ = u; \
    _Pragma("unroll") \
    for (int off = 32; off; off >>= 1) us_ += __shfl_xor(us_, off, 64); \
    OUT = ((float)C + __builtin_amdgcn_logf(us_)) * LN2; \
}
#define RSTEP(I) do { \
    if (t < hi) { \
        float g_ = __builtin_amdgcn_exp2f(fR##I * LOG2E); \
        int nr_ = t + 8; nr_ = nr_ < TT ? nr_ : TT - 1; \
        fR##I = col[(size_t)nr_ * LL]; \
        float a1 = 0.f, a2 = 0.f, a3 = 0.f, a4 = 0.f; \
        _Pragma("unroll") \
        for (int m = 0; m < 32; m += 4) { \
            int q0 = __builtin_amdgcn_readlane(upk, m); \
            int q1 = __builtin_amdgcn_readlane(upk, m + 1); \
            int q2 = __builtin_amdgcn_readlane(upk, m + 2); \
            int q3 = __builtin_amdgcn_readlane(upk, m + 3); \
            a1 = __builtin_amdgcn_fdot2(int_as_h2(q0), int_as_h2(ej[m]),     a1, false); \
            a2 = __builtin_amdgcn_fdot2(int_as_h2(q1), int_as_h2(ej[m + 1]), a2, false); \
            a3 = __builtin_amdgcn_fdot2(int_as_h2(q2), int_as_h2(ej[m + 2]), a3, false); \
            a4 = __builtin_amdgcn_fdot2(int_as_h2(q3), int_as_h2(ej[m + 3]), a4, false); \
        } \
        float v_ = ((a1 + a2) + (a3 + a4)) * g_; \
        RENORM(v_); \
        PACK(); \
        if (t == lo1) MEASURE(A_in); \
        ++t; \
    } \
} while (0)

    for (;;) {
        int ticket;
        if (lane == 0) ticket = (int)atomicAdd(counter, 1u);
        ticket = __shfl(ticket, 0, 64);
        if (ticket >= NITEM) break;

        const int s = (NSEG - 1) - (ticket >> 8);   // s descending in ticket order
        const int b = ticket & (BB - 1);
        const int slen = seq_lens[b];
        const int lo = 1 + SEG * s;

        if (s != 0 && lo >= slen) {                 // inactive segment: quick skip
            if (lane == 0) part[ticket] = 0.f;
            continue;
        }

        const int hi = (lo + SEG < slen) ? (lo + SEG) : slen;
        const float* lg  = logits + (size_t)b * TT * LL;
        const int*   lab = labels + b * TT;

        // ---- path-score portion for this segment's t-range ----
        float sc = 0.f;
        {
            int t0 = lo + lane;
            if (lane < SEG && t0 < hi) {
                int l1 = lab[t0];
                sc = lg[(size_t)t0 * LL + l1] + trans[lab[t0 - 1] * LL + l1];
            }
            if (s == 0 && lane == 0) sc += lg[lab[0]];   // t = 0 unary
            #pragma unroll
            for (int off = 32; off; off >>= 1) sc += __shfl_xor(sc, off, 64);
        }

        const int start = (s == 0) ? 1 : (lo - WARM);
        const int lo1   = (s == 0) ? -1 : (lo - 1);

        const float* col = lg + lane;
        int C = 0;
        float u;
        int upk;

        // init u from row start-1 (exact for s==0: row 0)
        {
            float v0 = __builtin_amdgcn_exp2f(col[(size_t)(start - 1) * LL] * LOG2E);
            RENORM(v0);
            PACK();
        }

        float A_in = 0.f, A_out;

        // ring preload: rows start .. start+7 (always < TT)
        float fR0 = col[(size_t)(start + 0) * LL];
        float fR1 = col[(size_t)(start + 1) * LL];
        float fR2 = col[(size_t)(start + 2) * LL];
        float fR3 = col[(size_t)(start + 3) * LL];
        float fR4 = col[(size_t)(start + 4) * LL];
        float fR5 = col[(size_t)(start + 5) * LL];
        float fR6 = col[(size_t)(start + 6) * LL];
        float fR7 = col[(size_t)(start + 7) * LL];

        int t = start;
        while (t < hi) {
            RSTEP(0); RSTEP(1); RSTEP(2); RSTEP(3);
            RSTEP(4); RSTEP(5); RSTEP(6); RSTEP(7);
        }

        MEASURE(A_out);
        if (lane == 0) part[ticket] = (A_out - A_in) - sc;
    }
}

__global__ __launch_bounds__(1024) void reduce_kernel(
    const float* __restrict__ part, float* __restrict__ out)
{
    int tid = threadIdx.x;
    float v = 0.f;
    #pragma unroll
    for (int i = 0; i < 8; ++i) v += part[tid + 1024 * i];
    #pragma unroll
    for (int off = 32; off; off >>= 1) v += __shfl_xor(v, off, 64);
    __shared__ float r[16];
    if ((tid & 63) == 0) r[tid >> 6] = v;
    __syncthreads();
    if (tid == 0) {
        float s = 0.f;
        #pragma unroll
        for (int i = 0; i < 16; ++i) s += r[i];
        out[0] = s;
    }
}

extern "C" void kernel_launch(void* const* d_in, const int* in_sizes, int n_in,
                              void* d_out, int out_size, void* d_ws, size_t ws_size,
                              hipStream_t stream) {
    const float* logits   = (const float*)d_in[0];
    const int*   labels   = (const int*)d_in[1];
    const int*   seq_lens = (const int*)d_in[2];
    const float* trans    = (const float*)d_in[3];

    unsigned int* counter = (unsigned int*)d_ws;          // 64-byte slot
    float* part = (float*)((char*)d_ws + 64);             // NITEM floats

    hipMemsetAsync(counter, 0, 64, stream);               // reset ticket queue
    crf_seg_kernel<<<1024, 256, 0, stream>>>(logits, labels, seq_lens, trans,
                                             counter, part);
    reduce_kernel<<<1, 1024, 0, stream>>>(part, (float*)d_out);
}

// Round 13
// 51.369 us; speedup vs baseline: 3.0997x; 3.0997x over previous
//
#include <hip/hip_runtime.h>

#define TT 1024
#define LL 64
#define BB 256             // batch
#define WARM 8             // warm-up steps per piece (contraction <= 0.462/step)
#define NWAVES 4096        // main-kernel waves (1024 blocks x 4)
#define LOG2E 1.44269504088896340736f
#define LN2   0.69314718055994530942f

typedef __fp16 half2v __attribute__((ext_vector_type(2)));
__device__ __forceinline__ half2v int_as_h2(int x) { union { int i; half2v h; } u; u.i = x; return u.h; }
__device__ __forceinline__ int h2_as_int(half2v x) { union { int i; half2v h; } u; u.h = x; return u.i; }

// EQUAL-WORK STATIC PARTITION. Pre-kernel: work_b = max(slen_b-1, 1),
// prefix-sum -> meta[0..256], K = ceil(W/NWAVES) -> meta[257]. Main kernel:
// wave wid owns global step range [wid*K, (wid+1)*K) and binary-searches the
// prefix table into contiguous per-sequence pieces. Every wave does exactly
// K real steps (+WARM per piece) -> zero load variance BY CONSTRUCTION,
// no atomics (round 12's queue serialized on cross-XCD atomics), fully
// deterministic. Piece [lo,hi) of seq b: warm-start at max(1, lo-WARM)
// (positive transfer operator: Hilbert diameter of E=exp(trans) <= 2 ->
// contraction tanh(0.5)=0.462/step; WARM=8 validated absmax 0.0 in r9-r11),
// delta = A(u@hi)-A(u@lo) telescopes to log_norm per sequence; lo==1 pieces
// are exact (init from row 0, A_in=0). slen=1 sequences get a virtual
// 1-unit piece that measures logsumexp(logits[0]) with an empty step loop.
// Each piece also scores its own unary+binary t-range (lo==1 adds unary(0)).
//
// Step, one state column per lane (unchanged from rounds 7-11):
//   v_j = (sum_m pair_m(u) . ej[m]) * exp(logit[t][j])   32 readlane + 32 fdot2
//   renorm by exact pow-2 of v_0 (readfirstlane exponent), C += e
//   repack pairs via 2 ds_bpermute + cvt_pkrtz
// Logit rows in an 8-slot named register ring (distance-8 prefetch),
// preload rows clamped to TT-1 (lo can reach 1022 now).

__global__ __launch_bounds__(256) void crf_prefix_kernel(
    const int* __restrict__ seq_lens, int* __restrict__ meta)
{
    __shared__ int sbuf[BB];
    const int tid = threadIdx.x;
    int wv = 0;
    if (tid < BB) { int sl = seq_lens[tid]; wv = (sl > 1) ? (sl - 1) : 1; }
    sbuf[tid] = wv;
    __syncthreads();
    for (int off = 1; off < BB; off <<= 1) {
        int v = (tid >= off) ? sbuf[tid - off] : 0;
        __syncthreads();
        sbuf[tid] += v;
        __syncthreads();
    }
    meta[tid + 1] = sbuf[tid];
    if (tid == 0) {
        meta[0] = 0;
        int W = sbuf[BB - 1];
        meta[BB + 1] = (W + NWAVES - 1) / NWAVES;   // K
    }
}

__global__ __launch_bounds__(256) void crf_piece_kernel(
    const float* __restrict__ logits,    // [B][T][L]
    const int*   __restrict__ labels,    // [B][T]
    const int*   __restrict__ seq_lens,  // [B]
    const float* __restrict__ trans,     // [L][L]
    const int*   __restrict__ meta,      // [258] prefix + K
    float*       __restrict__ part)      // [NWAVES]
{
    const int wid  = blockIdx.x * 4 + (threadIdx.x >> 6);
    const int lane = threadIdx.x & 63;

    // ---- one-time per wave: E-column pairs for this lane's column j = lane ----
    int ej[32];
    #pragma unroll
    for (int m = 0; m < 32; ++m) {
        half2v pp;
        pp[0] = (__fp16)__builtin_amdgcn_exp2f(trans[(2 * m)     * LL + lane] * LOG2E);
        pp[1] = (__fp16)__builtin_amdgcn_exp2f(trans[(2 * m + 1) * LL + lane] * LOG2E);
        ej[m] = h2_as_int(pp);
    }
    const int pad0 = (lane & 31) << 3;     // bpermute byte addr of lane 2k
    const int pad1 = pad0 + 4;             // lane 2k+1

    const int W = meta[BB];
    const int K = meta[BB + 1];
    int g0 = wid * K;
    int g1 = g0 + K; g1 = (g1 < W) ? g1 : W;

#define RENORM(V) { \
    int ebits = (__builtin_amdgcn_readfirstlane(__float_as_int(V)) >> 23) & 0xFF; \
    C += ebits - 127; \
    float scl = __int_as_float((254 - ebits) << 23); \
    u = (V) * scl; \
}
#define PACK() { \
    int pa_ = __builtin_amdgcn_ds_bpermute(pad0, __float_as_int(u)); \
    int pb_ = __builtin_amdgcn_ds_bpermute(pad1, __float_as_int(u)); \
    upk = h2_as_int(__builtin_amdgcn_cvt_pkrtz(__int_as_float(pa_), __int_as_float(pb_))); \
}
#define MEASURE(OUT) { \
    float us_ = u; \
    _Pragma("unroll") \
    for (int off = 32; off; off >>= 1) us_ += __shfl_xor(us_, off, 64); \
    OUT = ((float)C + __builtin_amdgcn_logf(us_)) * LN2; \
}
#define RSTEP(I) do { \
    if (t < hi) { \
        float g_ = __builtin_amdgcn_exp2f(fR##I * LOG2E); \
        int nr_ = t + 8; nr_ = nr_ < TT ? nr_ : TT - 1; \
        fR##I = col[(size_t)nr_ * LL]; \
        float a1 = 0.f, a2 = 0.f, a3 = 0.f, a4 = 0.f; \
        _Pragma("unroll") \
        for (int m = 0; m < 32; m += 4) { \
            int q0 = __builtin_amdgcn_readlane(upk, m); \
            int q1 = __builtin_amdgcn_readlane(upk, m + 1); \
            int q2 = __builtin_amdgcn_readlane(upk, m + 2); \
            int q3 = __builtin_amdgcn_readlane(upk, m + 3); \
            a1 = __builtin_amdgcn_fdot2(int_as_h2(q0), int_as_h2(ej[m]),     a1, false); \
            a2 = __builtin_amdgcn_fdot2(int_as_h2(q1), int_as_h2(ej[m + 1]), a2, false); \
            a3 = __builtin_amdgcn_fdot2(int_as_h2(q2), int_as_h2(ej[m + 2]), a3, false); \
            a4 = __builtin_amdgcn_fdot2(int_as_h2(q3), int_as_h2(ej[m + 3]), a4, false); \
        } \
        float v_ = ((a1 + a2) + (a3 + a4)) * g_; \
        RENORM(v_); \
        PACK(); \
        if (t == lo1) MEASURE(A_in); \
        ++t; \
    } \
} while (0)

    float result = 0.f;
    while (g0 < g1) {
        // binary search: largest b with meta[b] <= g0
        int blo = 0, bhi = BB;
        while (bhi - blo > 1) {
            int mid = (blo + bhi) >> 1;
            if (meta[mid] <= g0) blo = mid; else bhi = mid;
        }
        const int b  = blo;
        const int pe = meta[b + 1];
        const int units = ((g1 < pe) ? g1 : pe) - g0;
        const int lo = g0 - meta[b] + 1;
        const int slen = seq_lens[b];
        const int hi = (lo + units < slen) ? (lo + units) : slen;
        const float* lg  = logits + (size_t)b * TT * LL;
        const int*   lab = labels + b * TT;

        // ---- path-score portion for this piece's t-range ----
        float sc = 0.f;
        for (int t0 = lo + lane; t0 < hi; t0 += 64) {
            int l1 = lab[t0];
            sc += lg[(size_t)t0 * LL + l1] + trans[lab[t0 - 1] * LL + l1];
        }
        if (lo == 1 && lane == 0) sc += lg[lab[0]];   // t = 0 unary
        #pragma unroll
        for (int off = 32; off; off >>= 1) sc += __shfl_xor(sc, off, 64);

        const int start = (lo - WARM > 1) ? (lo - WARM) : 1;
        const int lo1   = (lo > 1) ? (lo - 1) : -1;   // A_in measure point

        const float* col = lg + lane;
        int C = 0;
        float u;
        int upk;

        // init u from row start-1 (exact when start==1: row 0)
        {
            float v0 = __builtin_amdgcn_exp2f(col[(size_t)(start - 1) * LL] * LOG2E);
            RENORM(v0);
            PACK();
        }

        float A_in = 0.f, A_out;

        // ring preload rows start..start+7, clamped (lo can reach 1022)
#define PLD(I) ((size_t)(((start + I) < TT) ? (start + I) : (TT - 1)) * LL)
        float fR0 = col[PLD(0)];
        float fR1 = col[PLD(1)];
        float fR2 = col[PLD(2)];
        float fR3 = col[PLD(3)];
        float fR4 = col[PLD(4)];
        float fR5 = col[PLD(5)];
        float fR6 = col[PLD(6)];
        float fR7 = col[PLD(7)];

        int t = start;
        while (t < hi) {
            RSTEP(0); RSTEP(1); RSTEP(2); RSTEP(3);
            RSTEP(4); RSTEP(5); RSTEP(6); RSTEP(7);
        }

        MEASURE(A_out);
        result += (A_out - A_in) - sc;
        g0 += units;
    }

    if (lane == 0) part[wid] = result;
}

__global__ __launch_bounds__(1024) void reduce_kernel(
    const float* __restrict__ part, float* __restrict__ out)
{
    int tid = threadIdx.x;
    float v = 0.f;
    #pragma unroll
    for (int i = 0; i < 4; ++i) v += part[tid + 1024 * i];
    #pragma unroll
    for (int off = 32; off; off >>= 1) v += __shfl_xor(v, off, 64);
    __shared__ float r[16];
    if ((tid & 63) == 0) r[tid >> 6] = v;
    __syncthreads();
    if (tid == 0) {
        float s = 0.f;
        #pragma unroll
        for (int i = 0; i < 16; ++i) s += r[i];
        out[0] = s;
    }
}

extern "C" void kernel_launch(void* const* d_in, const int* in_sizes, int n_in,
                              void* d_out, int out_size, void* d_ws, size_t ws_size,
                              hipStream_t stream) {
    const float* logits   = (const float*)d_in[0];
    const int*   labels   = (const int*)d_in[1];
    const int*   seq_lens = (const int*)d_in[2];
    const float* trans    = (const float*)d_in[3];

    int*   meta = (int*)d_ws;                         // 258 ints (<4 KB)
    float* part = (float*)((char*)d_ws + 4096);       // NWAVES floats

    crf_prefix_kernel<<<1, 256, 0, stream>>>(seq_lens, meta);
    crf_piece_kernel<<<1024, 256, 0, stream>>>(logits, labels, seq_lens, trans,
                                               meta, part);
    reduce_kernel<<<1, 1024, 0, stream>>>(part, (float*)d_out);
}